// Round 8
// baseline (188.484 us; speedup 1.0000x reference)
//
#include <hip/hip_runtime.h>
#include <stdint.h>

// ---------------------------------------------------------------------------
// CausalSelfAttention (B=2, T=2048, D=1024, H=16, Dh=64), fp32 in/out.
// cvt(fp32->bf16) -> QKV gemm (bf16 MFMA) -> flash attn (barrier-free 1-warp
// key-streams, 2-warp blocks, KVBLK=32, 16 waves/CU) -> out gemm.
// ---------------------------------------------------------------------------

typedef unsigned short u16;
typedef __attribute__((ext_vector_type(8)))  __bf16 bf16x8;   // 4 VGPR MFMA A/B frag
typedef __attribute__((ext_vector_type(4)))  float  f32x4;    // 16x16 C/D frag
typedef __attribute__((ext_vector_type(16))) float  f32x16;   // 32x32 C/D frag
typedef __attribute__((ext_vector_type(4)))  float  float4v;
typedef __attribute__((ext_vector_type(4)))  unsigned short u16x4;
typedef __attribute__((ext_vector_type(4)))  unsigned int   u32x4;
typedef __attribute__((ext_vector_type(8)))  short  short8;   // raw 16B load

#define BB 2
#define TT 2048
#define DD 1024
#define HH 16
#define DH 64
#define MM (BB*TT)          // 4096 rows

static __device__ __forceinline__ u16 f2bf(float f) {
    uint32_t u = __builtin_bit_cast(uint32_t, f);
    u += 0x7FFFu + ((u >> 16) & 1u);          // round-to-nearest-even
    return (u16)(u >> 16);
}

static __device__ __forceinline__ unsigned cvt_pk_bf16(float a, float b) {
    unsigned r;
    asm("v_cvt_pk_bf16_f32 %0, %1, %2" : "=v"(r) : "v"(a), "v"(b));
    return r;
}

// global(16B per lane) -> LDS direct copy (wave-uniform dst base + lane*16).
static __device__ __forceinline__ void load_lds16(const u16* g, const u16* lds_base) {
    __builtin_amdgcn_global_load_lds(
        (const __attribute__((address_space(1))) void*)(uintptr_t)g,
        (__attribute__((address_space(3)))  void*)(uint32_t)(uintptr_t)lds_base,
        16u, 0, 0u);
}

static __device__ __forceinline__ f32x4 mfma16(bf16x8 a, bf16x8 b, f32x4 c) {
    return __builtin_amdgcn_mfma_f32_16x16x32_bf16(a, b, c, 0, 0, 0);
}
static __device__ __forceinline__ f32x16 mfma32(bf16x8 a, bf16x8 b, f32x16 c) {
    return __builtin_amdgcn_mfma_f32_32x32x16_bf16(a, b, c, 0, 0, 0);
}

// balanced trees over the 16 per-lane score registers
static __device__ __forceinline__ float tree_max16(const f32x16& a) {
    float m[8];
#pragma unroll
    for (int r = 0; r < 8; ++r) m[r] = fmaxf(a[r], a[r + 8]);
#pragma unroll
    for (int off = 4; off; off >>= 1)
#pragma unroll
        for (int r = 0; r < off; ++r) m[r] = fmaxf(m[r], m[r + off]);
    return m[0];
}
static __device__ __forceinline__ float tree_sum16(const f32x16& a) {
    float m[8];
#pragma unroll
    for (int r = 0; r < 8; ++r) m[r] = a[r] + a[r + 8];
#pragma unroll
    for (int off = 4; off; off >>= 1)
#pragma unroll
        for (int r = 0; r < off; ++r) m[r] += m[r + off];
    return m[0];
}

// ------------------------------ fp32 -> bf16 -------------------------------
__global__ __launch_bounds__(256) void cvt_kernel(const float* __restrict__ src,
                                                  u16* __restrict__ dst, int n4) {
    int i = blockIdx.x * blockDim.x + threadIdx.x;
    int stride = gridDim.x * blockDim.x;
    for (; i < n4; i += stride) {
        float4v v = ((const float4v*)src)[i];
        u16x4 o;
        o[0] = f2bf(v[0]); o[1] = f2bf(v[1]); o[2] = f2bf(v[2]); o[3] = f2bf(v[3]);
        ((u16x4*)dst)[i] = o;
    }
}

// four matrices in one launch (z = blockIdx.y selects)
__global__ __launch_bounds__(256) void cvt4_kernel(const float* __restrict__ s0,
        const float* __restrict__ s1, const float* __restrict__ s2,
        const float* __restrict__ s3, u16* __restrict__ d0, u16* __restrict__ d1,
        u16* __restrict__ d2, u16* __restrict__ d3, int n4) {
    const int z = blockIdx.y;
    const float* src = (z == 0) ? s0 : (z == 1) ? s1 : (z == 2) ? s2 : s3;
    u16* dst = (z == 0) ? d0 : (z == 1) ? d1 : (z == 2) ? d2 : d3;
    int i = blockIdx.x * blockDim.x + threadIdx.x;
    int stride = gridDim.x * blockDim.x;
    for (; i < n4; i += stride) {
        float4v v = ((const float4v*)src)[i];
        u16x4 o;
        o[0] = f2bf(v[0]); o[1] = f2bf(v[1]); o[2] = f2bf(v[2]); o[3] = f2bf(v[3]);
        ((u16x4*)dst)[i] = o;
    }
}

// ------------------------- GEMM  C = A * W^T + bias ------------------------
// (unchanged m97-structure GEMM)
template<int OUTF32>
__global__ __launch_bounds__(256) void gemm_nt(const u16* __restrict__ A,
        const u16* __restrict__ W,
        const float* __restrict__ b0, const float* __restrict__ b1,
        const float* __restrict__ b2,
        u16* __restrict__ outb, float* __restrict__ outf,
        int M, int N, int K) {
    __shared__ alignas(16) u16 As[128 * 32];
    __shared__ alignas(16) u16 Bs[128 * 32];

    const int tid  = threadIdx.x;
    const int wave = tid >> 6, lane = tid & 63;
    const int lr = lane & 15, lg = lane >> 4;
    const int wr = wave >> 1, wc = wave & 1;
    const int z  = blockIdx.z;
    const int m0 = blockIdx.x * 128;
    const int n0 = blockIdx.y * 128;

    const u16* Wz = W + (size_t)z * N * K;
    const float* bias = (z == 0) ? b0 : (z == 1) ? b1 : b2;

    f32x4 acc[4][4];
#pragma unroll
    for (int m = 0; m < 4; ++m)
#pragma unroll
        for (int n = 0; n < 4; ++n) acc[m][n] = (f32x4){0.f, 0.f, 0.f, 0.f};

    for (int k0 = 0; k0 < K; k0 += 32) {
        __syncthreads();
#pragma unroll
        for (int it = 0; it < 2; ++it) {
            int c = it * 256 + tid;
            int row = c >> 2, cc = (c & 3) * 8;
            const u16* gA = A  + (size_t)(m0 + row) * K + k0 + cc;
            const u16* gB = Wz + (size_t)(n0 + row) * K + k0 + cc;
            load_lds16(gA, As + (size_t)(it * 256 + wave * 64) * 8);
            load_lds16(gB, Bs + (size_t)(it * 256 + wave * 64) * 8);
        }
        __syncthreads();

        bf16x8 af[4], bfm[4];
#pragma unroll
        for (int m = 0; m < 4; ++m)
            af[m] = *(const bf16x8*)&As[(wr * 64 + m * 16 + lr) * 32 + lg * 8];
#pragma unroll
        for (int n = 0; n < 4; ++n)
            bfm[n] = *(const bf16x8*)&Bs[(wc * 64 + n * 16 + lr) * 32 + lg * 8];
#pragma unroll
        for (int m = 0; m < 4; ++m)
#pragma unroll
            for (int n = 0; n < 4; ++n)
                acc[m][n] = mfma16(af[m], bfm[n], acc[m][n]);
    }

#pragma unroll
    for (int n = 0; n < 4; ++n) {
        int col = n0 + wc * 64 + n * 16 + lr;
        float bv = bias[col];
#pragma unroll
        for (int m = 0; m < 4; ++m) {
            int row = m0 + wr * 64 + m * 16 + lg * 4;
#pragma unroll
            for (int r = 0; r < 4; ++r) {
                float v = acc[m][n][r] + bv;
                if (OUTF32 == 0)
                    outb[(size_t)z * M * N + (size_t)(row + r) * N + col] = f2bf(v);
                else
                    outf[(size_t)(row + r) * N + col] = v;
            }
        }
    }
}

// ------------------------------- attention ---------------------------------
// grid (64, 32) remapped XCD-aware: id -> xcd=id&7, bh=xcd*4+(id>>3)/64,
// qi=(id>>3)&63. Block = 128 threads = 2 warps, both owning q rows
// [qi*32, qi*32+32); warp pa handles KV tiles t = pa, pa+2, ... (KVBLK=32).
// Each warp privately stages K (global_load_lds, swizzled src) and V^T
// (coalesced read, strided write) into its own LDS half -> NO per-tile
// barriers. Swapped 32x32 MFMA (S^T = K.Q^T, lane owns one q col), in-lane
// softmax, O^T = V^T.P^T. One __syncthreads for the end pair-merge.
// 18.4KB LDS, target VGPR<=128 -> 8 blocks/CU = 16 waves/CU = 4 waves/SIMD.
__global__ __launch_bounds__(128) void attn_kernel(const u16* __restrict__ Qb,
        const u16* __restrict__ Kb, const u16* __restrict__ Vb,
        u16* __restrict__ Yb) {
    // per-warp region: K[32][64] (2048 u16) + Vt[64][40] (2560 u16)
    // merge overlay in pool[1]: o f32[64*33] + m/l f32[2][32]
    __shared__ alignas(16) u16 pool[2][4608];

    const int tid  = threadIdx.x;
    const int pa   = tid >> 6;                // warp 0: even tiles, 1: odd
    const int lane = tid & 63;
    const int lq = lane & 31, hi = lane >> 5;

    const int id  = blockIdx.y * 64 + blockIdx.x;
    const int slot = id >> 3;
    const int bh = (id & 7) * 4 + (slot >> 6);   // XCD-local head group
    const int qi = slot & 63;
    const int b = bh >> 4, h = bh & 15;
    const size_t rb = (size_t)b * TT;
    const int hoff = h * DH;
    const int q0 = qi * 32;
    const int nt = qi + 1;                    // 32-key tiles needed

    u16* Kp  = pool[pa];
    u16* Vtp = pool[pa] + 2048;
    const u16* Kbh = Kb + rb * DD + hoff;
    const u16* Vbh = Vb + rb * DD + hoff;

    // Q fragments (B-operand): col=lane&31=q, k=(lane>>5)*8+j ; 4 chunks of 16
    bf16x8 qf[4];
    {
        const u16* qrow = Qb + (rb + q0 + lq) * DD + hoff + hi * 8;
#pragma unroll
        for (int kc = 0; kc < 4; ++kc) qf[kc] = *(const bf16x8*)(qrow + kc * 16);
    }

    f32x16 o0 = {}, o1 = {};
    float m_i = -1e30f, l_i = 0.f;
    const float cexp = 0.18033688011f;        // 0.125 * log2(e)

    for (int t = pa; t < nt; t += 2) {
        const u16* Kt = Kbh + (size_t)(t * 32) * DD;
        const u16* Vt0 = Vbh + (size_t)(t * 32) * DD;

        // ---- stage K: 4 x global_load_lds (1KB each), swizzled source
#pragma unroll
        for (int it = 0; it < 4; ++it) {
            int c = it * 64 + lane;
            int row = c >> 3, sl = c & 7;
            load_lds16(Kt + (size_t)row * DD + ((sl ^ (row & 7)) * 8),
                       Kp + (size_t)it * 512);
        }
        // ---- load V coalesced (8 lanes per 128B row), then strided V^T write
        short8 vr[4];
#pragma unroll
        for (int it = 0; it < 4; ++it) {
            int c = it * 64 + lane;
            vr[it] = *(const short8*)(Vt0 + (size_t)(c >> 3) * DD + (c & 7) * 8);
        }
#pragma unroll
        for (int it = 0; it < 4; ++it) {
            int c = it * 64 + lane;
            int key = c >> 3, d0 = (c & 7) * 8;
#pragma unroll
            for (int j = 0; j < 8; ++j) Vtp[(d0 + j) * 40 + key] = (u16)vr[it][j];
        }
        // ensure this warp's K gload_lds landed before reading (rule 18)
        asm volatile("s_waitcnt vmcnt(0)" ::: "memory");
        __builtin_amdgcn_sched_barrier(0);

        // S^T[key][q] = K.Q^T : A=K (row=key 0..31, swizzled read), B=Q
        f32x16 st = {};
        const int rowm = lq & 7;
#pragma unroll
        for (int kc = 0; kc < 4; ++kc) {
            bf16x8 kf = *(const bf16x8*)&Kp[lq * 64 + ((2 * kc + hi) ^ rowm) * 8];
            st = mfma32(kf, qf[kc], st);
        }

        // causal mask only on the block's last tile (owned by warp qi&1)
        if (t == nt - 1) {
#pragma unroll
            for (int r = 0; r < 16; ++r) {
                int key = (r & 3) + 8 * (r >> 2) + 4 * hi;
                if (key > lq) st[r] = -1e30f;
            }
        }

        // online softmax, fully in-lane
        float pm = tree_max16(st);
        pm = fmaxf(pm, __shfl_xor(pm, 32));
        if (!__all(pm - m_i <= 44.3614f)) {      // defer-max (T13)
            const float mnew  = fmaxf(m_i, pm);
            const float alpha = __builtin_amdgcn_exp2f((m_i - mnew) * cexp);
            l_i *= alpha;
#pragma unroll
            for (int r = 0; r < 16; ++r) { o0[r] *= alpha; o1[r] *= alpha; }
            m_i = mnew;
        }
#pragma unroll
        for (int r = 0; r < 16; ++r)
            st[r] = __builtin_amdgcn_exp2f((st[r] - m_i) * cexp);
        float rs = tree_sum16(st);
        rs += __shfl_xor(rs, 32);
        l_i += rs;

        // P^T -> B-operand frags (cvt_pk + permlane32_swap, T12)
        bf16x8 pb[2];
#pragma unroll
        for (int ks = 0; ks < 2; ++ks) {
            const int base = 8 * ks;
            unsigned c0 = cvt_pk_bf16(st[base + 0], st[base + 1]);
            unsigned c1 = cvt_pk_bf16(st[base + 2], st[base + 3]);
            unsigned c2 = cvt_pk_bf16(st[base + 4], st[base + 5]);
            unsigned c3 = cvt_pk_bf16(st[base + 6], st[base + 7]);
            asm volatile("v_permlane32_swap_b32 %0, %1" : "+v"(c0), "+v"(c2));
            asm volatile("v_permlane32_swap_b32 %0, %1" : "+v"(c1), "+v"(c3));
            u32x4 w; w[0] = c0; w[1] = c1; w[2] = c2; w[3] = c3;
            pb[ks] = __builtin_bit_cast(bf16x8, w);
        }

        // O^T += V^T . P^T : A=V^T (row=d), B=P^T (col=q)
#pragma unroll
        for (int ks = 0; ks < 2; ++ks) {
            bf16x8 vf0 = *(const bf16x8*)&Vtp[(lq)      * 40 + ks * 16 + hi * 8];
            bf16x8 vf1 = *(const bf16x8*)&Vtp[(32 + lq) * 40 + ks * 16 + hi * 8];
            o0 = mfma32(vf0, pb[ks], o0);
            o1 = mfma32(vf1, pb[ks], o1);
        }
    }

    // ---- pair merge: warp1 publishes partials in ITS OWN region, one barrier
    if (pa == 1) {
        float* ob  = (float*)pool[1];                  // [64 lanes][33]
        float* mlp = (float*)pool[1] + 64 * 33;        // m[32], l[32]
#pragma unroll
        for (int r = 0; r < 16; ++r) {
            ob[lane * 33 + r]      = o0[r];
            ob[lane * 33 + 16 + r] = o1[r];
        }
        if (hi == 0) { mlp[lq] = m_i; mlp[32 + lq] = l_i; }
    }
    __syncthreads();
    if (pa == 0) {
        const float* ob  = (const float*)pool[1];
        const float* mlp = (const float*)pool[1] + 64 * 33;
        const float mB = mlp[lq], lB = mlp[32 + lq];
        const float mm = fmaxf(m_i, mB);
        const float sA = __builtin_amdgcn_exp2f((m_i - mm) * cexp);
        const float sB = __builtin_amdgcn_exp2f((mB  - mm) * cexp);
        const float inv = 1.0f / (l_i * sA + lB * sB);
        const float* obl = ob + lane * 33;
        u16* yrow = Yb + (rb + q0 + lq) * DD + hoff;
#pragma unroll
        for (int g = 0; g < 4; ++g) {
            u16x4 p0, p1;
#pragma unroll
            for (int j = 0; j < 4; ++j) {
                p0[j] = f2bf((o0[4 * g + j] * sA + obl[4 * g + j]      * sB) * inv);
                p1[j] = f2bf((o1[4 * g + j] * sA + obl[16 + 4 * g + j] * sB) * inv);
            }
            *(u16x4*)&yrow[8 * g + 4 * hi]      = p0;
            *(u16x4*)&yrow[32 + 8 * g + 4 * hi] = p1;
        }
    }
}

// ------------------------------- launcher ----------------------------------
extern "C" void kernel_launch(void* const* d_in, const int* in_sizes, int n_in,
                              void* d_out, int out_size, void* d_ws, size_t ws_size,
                              hipStream_t stream) {
    const float* x  = (const float*)d_in[0];
    const float* Wq = (const float*)d_in[1];
    const float* bq = (const float*)d_in[2];
    const float* Wk = (const float*)d_in[3];
    const float* bk = (const float*)d_in[4];
    const float* Wv = (const float*)d_in[5];
    const float* bv = (const float*)d_in[6];
    const float* Wo = (const float*)d_in[7];
    const float* bo = (const float*)d_in[8];
    float* out = (float*)d_out;

    const size_t XN = (size_t)MM * DD;   // 4,194,304
    const size_t WN = (size_t)DD * DD;   // 1,048,576

    u16* xb  = (u16*)d_ws;
    u16* Wb  = xb  + XN;          // Wq,Wk,Wv stacked: 3*WN
    u16* Wob = Wb  + 3 * WN;
    u16* QKV = Wob + WN;          // Q,K,V stacked: 3*XN
    u16* Yb  = QKV + 3 * XN;

    cvt_kernel<<<2048, 256, 0, stream>>>(x, xb, (int)(XN / 4));
    cvt4_kernel<<<dim3(256, 4), 256, 0, stream>>>(Wq, Wk, Wv, Wo,
            Wb, Wb + WN, Wb + 2 * WN, Wob, (int)(WN / 4));

    gemm_nt<0><<<dim3(32, 8, 3), 256, 0, stream>>>(xb, Wb, bq, bk, bv,
                                                   QKV, nullptr, MM, DD, DD);
    attn_kernel<<<dim3(64, 32), 128, 0, stream>>>(QKV, QKV + XN,
                                                  QKV + 2 * XN, Yb);
    gemm_nt<1><<<dim3(32, 8, 1), 256, 0, stream>>>(Yb, Wob, bo, bo, bo,
                                                   nullptr, out, MM, DD, DD);
}

// Round 9
// 143.647 us; speedup vs baseline: 1.3121x; 1.3121x over previous
//
#include <hip/hip_runtime.h>
#include <stdint.h>

// ---------------------------------------------------------------------------
// CausalSelfAttention (B=2, T=2048, D=1024, H=16, Dh=64), fp32 in/out.
// cvt -> QKV gemm -> flash attn: PASS1 = KV-split partials (uniform 256-key
// chunks, 2304 blocks), PASS2 = (m,l)-weighted merge -> out gemm.
// ---------------------------------------------------------------------------

typedef unsigned short u16;
typedef __attribute__((ext_vector_type(8)))  __bf16 bf16x8;   // 4 VGPR MFMA A/B frag
typedef __attribute__((ext_vector_type(4)))  float  f32x4;    // 16x16 C/D frag
typedef __attribute__((ext_vector_type(16))) float  f32x16;   // 32x32 C/D frag
typedef __attribute__((ext_vector_type(4)))  float  float4v;
typedef __attribute__((ext_vector_type(4)))  unsigned short u16x4;
typedef __attribute__((ext_vector_type(4)))  unsigned int   u32x4;
typedef __attribute__((ext_vector_type(8)))  short  short8;   // raw 16B load

#define BB 2
#define TT 2048
#define DD 1024
#define HH 16
#define DH 64
#define MM (BB*TT)          // 4096 rows
#define NSLOT 2304          // 32 bh * 72 (qi,chunk) slots

static __device__ __forceinline__ u16 f2bf(float f) {
    uint32_t u = __builtin_bit_cast(uint32_t, f);
    u += 0x7FFFu + ((u >> 16) & 1u);          // round-to-nearest-even
    return (u16)(u >> 16);
}
static __device__ __forceinline__ float bf2f(u16 v) {
    uint32_t u = (uint32_t)v << 16;
    return __builtin_bit_cast(float, u);
}

static __device__ __forceinline__ unsigned cvt_pk_bf16(float a, float b) {
    unsigned r;
    asm("v_cvt_pk_bf16_f32 %0, %1, %2" : "=v"(r) : "v"(a), "v"(b));
    return r;
}

// global(16B per lane) -> LDS direct copy (wave-uniform dst base + lane*16).
static __device__ __forceinline__ void load_lds16(const u16* g, const u16* lds_base) {
    __builtin_amdgcn_global_load_lds(
        (const __attribute__((address_space(1))) void*)(uintptr_t)g,
        (__attribute__((address_space(3)))  void*)(uint32_t)(uintptr_t)lds_base,
        16u, 0, 0u);
}

static __device__ __forceinline__ f32x4 mfma16(bf16x8 a, bf16x8 b, f32x4 c) {
    return __builtin_amdgcn_mfma_f32_16x16x32_bf16(a, b, c, 0, 0, 0);
}
static __device__ __forceinline__ f32x16 mfma32(bf16x8 a, bf16x8 b, f32x16 c) {
    return __builtin_amdgcn_mfma_f32_32x32x16_bf16(a, b, c, 0, 0, 0);
}

// balanced trees over the 32 per-lane score registers
static __device__ __forceinline__ float tree_max32(const f32x16& a, const f32x16& b) {
    float m[16];
#pragma unroll
    for (int r = 0; r < 16; ++r) m[r] = fmaxf(a[r], b[r]);
#pragma unroll
    for (int off = 8; off; off >>= 1)
#pragma unroll
        for (int r = 0; r < off; ++r) m[r] = fmaxf(m[r], m[r + off]);
    return m[0];
}
static __device__ __forceinline__ float tree_sum32(const f32x16& a, const f32x16& b) {
    float m[16];
#pragma unroll
    for (int r = 0; r < 16; ++r) m[r] = a[r] + b[r];
#pragma unroll
    for (int off = 8; off; off >>= 1)
#pragma unroll
        for (int r = 0; r < off; ++r) m[r] += m[r + off];
    return m[0];
}

// ------------------------------ fp32 -> bf16 -------------------------------
__global__ __launch_bounds__(256) void cvt_kernel(const float* __restrict__ src,
                                                  u16* __restrict__ dst, int n4) {
    int i = blockIdx.x * blockDim.x + threadIdx.x;
    int stride = gridDim.x * blockDim.x;
    for (; i < n4; i += stride) {
        float4v v = ((const float4v*)src)[i];
        u16x4 o;
        o[0] = f2bf(v[0]); o[1] = f2bf(v[1]); o[2] = f2bf(v[2]); o[3] = f2bf(v[3]);
        ((u16x4*)dst)[i] = o;
    }
}

// four matrices in one launch (z = blockIdx.y selects)
__global__ __launch_bounds__(256) void cvt4_kernel(const float* __restrict__ s0,
        const float* __restrict__ s1, const float* __restrict__ s2,
        const float* __restrict__ s3, u16* __restrict__ d0, u16* __restrict__ d1,
        u16* __restrict__ d2, u16* __restrict__ d3, int n4) {
    const int z = blockIdx.y;
    const float* src = (z == 0) ? s0 : (z == 1) ? s1 : (z == 2) ? s2 : s3;
    u16* dst = (z == 0) ? d0 : (z == 1) ? d1 : (z == 2) ? d2 : d3;
    int i = blockIdx.x * blockDim.x + threadIdx.x;
    int stride = gridDim.x * blockDim.x;
    for (; i < n4; i += stride) {
        float4v v = ((const float4v*)src)[i];
        u16x4 o;
        o[0] = f2bf(v[0]); o[1] = f2bf(v[1]); o[2] = f2bf(v[2]); o[3] = f2bf(v[3]);
        ((u16x4*)dst)[i] = o;
    }
}

// ------------------------- GEMM  C = A * W^T + bias ------------------------
// (unchanged m97-structure GEMM)
template<int OUTF32>
__global__ __launch_bounds__(256) void gemm_nt(const u16* __restrict__ A,
        const u16* __restrict__ W,
        const float* __restrict__ b0, const float* __restrict__ b1,
        const float* __restrict__ b2,
        u16* __restrict__ outb, float* __restrict__ outf,
        int M, int N, int K) {
    __shared__ alignas(16) u16 As[128 * 32];
    __shared__ alignas(16) u16 Bs[128 * 32];

    const int tid  = threadIdx.x;
    const int wave = tid >> 6, lane = tid & 63;
    const int lr = lane & 15, lg = lane >> 4;
    const int wr = wave >> 1, wc = wave & 1;
    const int z  = blockIdx.z;
    const int m0 = blockIdx.x * 128;
    const int n0 = blockIdx.y * 128;

    const u16* Wz = W + (size_t)z * N * K;
    const float* bias = (z == 0) ? b0 : (z == 1) ? b1 : b2;

    f32x4 acc[4][4];
#pragma unroll
    for (int m = 0; m < 4; ++m)
#pragma unroll
        for (int n = 0; n < 4; ++n) acc[m][n] = (f32x4){0.f, 0.f, 0.f, 0.f};

    for (int k0 = 0; k0 < K; k0 += 32) {
        __syncthreads();
#pragma unroll
        for (int it = 0; it < 2; ++it) {
            int c = it * 256 + tid;
            int row = c >> 2, cc = (c & 3) * 8;
            const u16* gA = A  + (size_t)(m0 + row) * K + k0 + cc;
            const u16* gB = Wz + (size_t)(n0 + row) * K + k0 + cc;
            load_lds16(gA, As + (size_t)(it * 256 + wave * 64) * 8);
            load_lds16(gB, Bs + (size_t)(it * 256 + wave * 64) * 8);
        }
        __syncthreads();

        bf16x8 af[4], bfm[4];
#pragma unroll
        for (int m = 0; m < 4; ++m)
            af[m] = *(const bf16x8*)&As[(wr * 64 + m * 16 + lr) * 32 + lg * 8];
#pragma unroll
        for (int n = 0; n < 4; ++n)
            bfm[n] = *(const bf16x8*)&Bs[(wc * 64 + n * 16 + lr) * 32 + lg * 8];
#pragma unroll
        for (int m = 0; m < 4; ++m)
#pragma unroll
            for (int n = 0; n < 4; ++n)
                acc[m][n] = mfma16(af[m], bfm[n], acc[m][n]);
    }

#pragma unroll
    for (int n = 0; n < 4; ++n) {
        int col = n0 + wc * 64 + n * 16 + lr;
        float bv = bias[col];
#pragma unroll
        for (int m = 0; m < 4; ++m) {
            int row = m0 + wr * 64 + m * 16 + lg * 4;
#pragma unroll
            for (int r = 0; r < 4; ++r) {
                float v = acc[m][n][r] + bv;
                if (OUTF32 == 0)
                    outb[(size_t)z * M * N + (size_t)(row + r) * N + col] = f2bf(v);
                else
                    outf[(size_t)(row + r) * N + col] = v;
            }
        }
    }
}

// --------------------------- attention pass 1 ------------------------------
// KV-split flash partials. Grid 2304 = 32 bh x 72 (qi,chunk) slots where
// qi = 128-row q tile (0..15), chunk = 256-key range; nch(qi) = (qi+2)>>1.
// Block = 256 thr (4 warps x 32 q). Inner loop = r3's proven body (K via
// global_load_lds + XOR swizzle, lane=key V^T transpose write (conflict-free),
// swapped 32x32 MFMA, in-lane softmax, T12, defer-max). <=4 uniform tiles
// per block -> no causal tail, ~9 blocks/CU of uniform work.
// Partials: Op[slot][64 d][128 q] bf16 (unnormalized O^T), Ml[slot][2][128].
__global__ __launch_bounds__(256) void attn_part(const u16* __restrict__ Qb,
        const u16* __restrict__ Kb, const u16* __restrict__ Vb,
        u16* __restrict__ Op, float* __restrict__ Ml) {
    __shared__ alignas(16) u16 Ks[64 * 64];   // [key][d], XOR-swizzled 16B slots
    __shared__ alignas(16) u16 Vt[64 * 72];   // [d][key], stride 72

    const int tid  = threadIdx.x;
    const int wave = tid >> 6, lane = tid & 63;
    const int lq = lane & 31, hi = lane >> 5;

    const int id = blockIdx.x;
    const int bh = id / 72;
    const int s  = id - bh * 72;
    int qi = 0, ch = 0;
    {
        int cum = 0, found = 0;
#pragma unroll
        for (int j = 0; j < 16; ++j) {
            int n = (j + 2) >> 1;
            if (!found && s < cum + n) { qi = j; ch = s - cum; found = 1; }
            cum += n;
        }
    }
    const int b = bh >> 4, h = bh & 15;
    const size_t rb = (size_t)b * TT;
    const int hoff = h * DH;
    const int q0w = qi * 128 + wave * 32;     // warp q base
    const int k0 = ch * 256;
    const int k1 = min(k0 + 256, qi * 128 + 128);

    // staging coordinates (r3 patterns)
    const int krow0 = tid >> 3, ks0 = tid & 7;           // K chunk, it=0
    const int krow1 = (256 + tid) >> 3, ks1 = tid & 7;   // K chunk, it=1
    const int vkey = tid & 63;                           // V row (lane=key)
    const int vd0a = (tid >> 6) * 8, vd0b = vd0a + 32;   // V d-ranges

    const u16* Kbh = Kb + rb * DD + hoff;
    const u16* Vbh = Vb + rb * DD + hoff;

    // Q fragments (B-operand): col=lane&31=q, k=(lane>>5)*8+j ; 4 chunks of 16
    bf16x8 qf[4];
    {
        const u16* qrow = Qb + (rb + q0w + lq) * DD + hoff + hi * 8;
#pragma unroll
        for (int kc = 0; kc < 4; ++kc) qf[kc] = *(const bf16x8*)(qrow + kc * 16);
    }

    f32x16 o0 = {}, o1 = {};
    float m_i = -1e30f, l_i = 0.f;
    const float cexp = 0.18033688011f;        // 0.125 * log2(e)

    for (int kv0 = k0; kv0 < k1; kv0 += 64) {
        __syncthreads();
        // ---- stage K via global_load_lds (swizzled source, linear dest)
        load_lds16(Kbh + (size_t)(kv0 + krow0) * DD + (ks0 ^ (krow0 & 7)) * 8,
                   &Ks[(size_t)(wave * 64) * 8]);
        load_lds16(Kbh + (size_t)(kv0 + krow1) * DD + (ks1 ^ (krow1 & 7)) * 8,
                   &Ks[(size_t)(256 + wave * 64) * 8]);
        // ---- stage V^T (lane=key gather read, conflict-free strided write)
        {
            const u16* vrow = Vbh + (size_t)(kv0 + vkey) * DD;
            short8 v0 = *(const short8*)(vrow + vd0a);
            short8 v1 = *(const short8*)(vrow + vd0b);
#pragma unroll
            for (int j = 0; j < 8; ++j) {
                Vt[(vd0a + j) * 72 + vkey] = (u16)v0[j];
                Vt[(vd0b + j) * 72 + vkey] = (u16)v1[j];
            }
        }
        __syncthreads();

        if (kv0 < q0w + 32) {   // not fully masked for this warp
            // S^T[key][q] = K.Q^T : A=K (row=key, swizzled read), B=Q (col=q)
            f32x16 st0 = {}, st1 = {};
            const int rowm = lq & 7;
#pragma unroll
            for (int kc = 0; kc < 4; ++kc) {
                bf16x8 kk = *(const bf16x8*)&Ks[(lq) * 64 + ((2 * kc + hi) ^ rowm) * 8];
                st0 = mfma32(kk, qf[kc], st0);
            }
#pragma unroll
            for (int kc = 0; kc < 4; ++kc) {
                bf16x8 kk = *(const bf16x8*)&Ks[(32 + lq) * 64 + ((2 * kc + hi) ^ rowm) * 8];
                st1 = mfma32(kk, qf[kc], st1);
            }

            // causal mask on raw scores
            if (kv0 + 63 > q0w) {
                const int qrel = q0w + lq - kv0;
#pragma unroll
                for (int r = 0; r < 16; ++r) {
                    int key = (r & 3) + 8 * (r >> 2) + 4 * hi;
                    if (key      > qrel) st0[r] = -1e30f;
                    if (key + 32 > qrel) st1[r] = -1e30f;
                }
            }

            // online softmax, in-lane tree reduces + defer-max (T13)
            float pm = tree_max32(st0, st1);
            pm = fmaxf(pm, __shfl_xor(pm, 32));
            if (!__all(pm - m_i <= 44.3614f)) {
                const float mnew  = fmaxf(m_i, pm);
                const float alpha = __builtin_amdgcn_exp2f((m_i - mnew) * cexp);
                l_i *= alpha;
#pragma unroll
                for (int r = 0; r < 16; ++r) { o0[r] *= alpha; o1[r] *= alpha; }
                m_i = mnew;
            }
#pragma unroll
            for (int r = 0; r < 16; ++r) {
                st0[r] = __builtin_amdgcn_exp2f((st0[r] - m_i) * cexp);
                st1[r] = __builtin_amdgcn_exp2f((st1[r] - m_i) * cexp);
            }
            float rs = tree_sum32(st0, st1);
            rs += __shfl_xor(rs, 32);
            l_i += rs;

            // P^T -> B-operand frags: cvt_pk pairs + permlane32_swap (T12)
            bf16x8 pb[4];
#pragma unroll
            for (int ks = 0; ks < 4; ++ks) {
                const f32x16& sb = (ks < 2) ? st0 : st1;
                const int base = 8 * (ks & 1);
                unsigned c0 = cvt_pk_bf16(sb[base + 0], sb[base + 1]);
                unsigned c1 = cvt_pk_bf16(sb[base + 2], sb[base + 3]);
                unsigned c2 = cvt_pk_bf16(sb[base + 4], sb[base + 5]);
                unsigned c3 = cvt_pk_bf16(sb[base + 6], sb[base + 7]);
                asm volatile("v_permlane32_swap_b32 %0, %1" : "+v"(c0), "+v"(c2));
                asm volatile("v_permlane32_swap_b32 %0, %1" : "+v"(c1), "+v"(c3));
                u32x4 w; w[0] = c0; w[1] = c1; w[2] = c2; w[3] = c3;
                pb[ks] = __builtin_bit_cast(bf16x8, w);
            }

            // O^T += V^T . P^T : A=V^T (row=d), B=P^T (col=q)
#pragma unroll
            for (int ks = 0; ks < 4; ++ks) {
                bf16x8 vf0 = *(const bf16x8*)&Vt[(lq)      * 72 + ks * 16 + hi * 8];
                bf16x8 vf1 = *(const bf16x8*)&Vt[(32 + lq) * 72 + ks * 16 + hi * 8];
                o0 = mfma32(vf0, pb[ks], o0);
                o1 = mfma32(vf1, pb[ks], o1);
            }
        }
    }

    // ---- write partials: Op[slot][d 0..63][q 0..127] bf16 (unnormalized),
    // Ml[slot][0][q]=m, [1][q]=l (raw-score base used for the exps)
    u16* op = Op + (size_t)id * 8192;
    const int col = wave * 32 + lq;
#pragma unroll
    for (int r = 0; r < 16; ++r) {
        const int d0 = (r & 3) + 8 * (r >> 2) + 4 * hi;
        op[d0 * 128 + col]        = f2bf(o0[r]);
        op[(32 + d0) * 128 + col] = f2bf(o1[r]);
    }
    if (hi == 0) {
        Ml[(size_t)id * 256 + col]       = m_i;
        Ml[(size_t)id * 256 + 128 + col] = l_i;
    }
}

// --------------------------- attention pass 2 ------------------------------
// grid 512 = 32 bh x 16 qi; 256 thr. Thread t: row = t>>1 (0..127),
// dh = (t&1)*32. Combines nch(qi) partials: O = sum_c O_c*2^((m_c-m*)cexp)
// / sum_c l_c*2^((m_c-m*)cexp). All chunk loops fully unrolled (rule #20).
__global__ __launch_bounds__(256) void attn_merge(const u16* __restrict__ Op,
        const float* __restrict__ Ml, u16* __restrict__ Yb) {
    const int bq = blockIdx.x;
    const int bh = bq >> 4, qi = bq & 15;
    const int nc = (qi + 2) >> 1;
    int cum = 0;
#pragma unroll
    for (int j = 0; j < 16; ++j) cum += (j < qi) ? ((j + 2) >> 1) : 0;
    const int s0 = bh * 72 + cum;

    const int t = threadIdx.x;
    const int row = t >> 1, dh = (t & 1) * 32;
    const float cexp = 0.18033688011f;

    float mc[8], lc[8];
#pragma unroll
    for (int c = 0; c < 8; ++c) {
        if (c < nc) {
            mc[c] = Ml[(size_t)(s0 + c) * 256 + row];
            lc[c] = Ml[(size_t)(s0 + c) * 256 + 128 + row];
        } else { mc[c] = -1e30f; lc[c] = 0.f; }
    }
    float mx = mc[0];
#pragma unroll
    for (int c = 1; c < 8; ++c) mx = fmaxf(mx, mc[c]);
    float w[8], L = 0.f;
#pragma unroll
    for (int c = 0; c < 8; ++c) {
        w[c] = __builtin_amdgcn_exp2f((mc[c] - mx) * cexp);
        L += lc[c] * w[c];
    }
    const float inv = 1.0f / L;
#pragma unroll
    for (int c = 0; c < 8; ++c) w[c] *= inv;

    float acc[32];
#pragma unroll
    for (int d = 0; d < 32; ++d) acc[d] = 0.f;
#pragma unroll
    for (int c = 0; c < 8; ++c) {
        if (c < nc) {
            const u16* op = Op + (size_t)(s0 + c) * 8192 + row;
#pragma unroll
            for (int d = 0; d < 32; ++d)
                acc[d] += bf2f(op[(dh + d) * 128]) * w[c];
        }
    }

    const int b = bh >> 4, h = bh & 15;
    u16* yrow = Yb + ((size_t)(b * TT + qi * 128 + row)) * DD + h * DH + dh;
#pragma unroll
    for (int g = 0; g < 8; ++g) {
        u16x4 p;
#pragma unroll
        for (int j = 0; j < 4; ++j) p[j] = f2bf(acc[4 * g + j]);
        *(u16x4*)&yrow[4 * g] = p;
    }
}

// ------------------------------- launcher ----------------------------------
extern "C" void kernel_launch(void* const* d_in, const int* in_sizes, int n_in,
                              void* d_out, int out_size, void* d_ws, size_t ws_size,
                              hipStream_t stream) {
    const float* x  = (const float*)d_in[0];
    const float* Wq = (const float*)d_in[1];
    const float* bq = (const float*)d_in[2];
    const float* Wk = (const float*)d_in[3];
    const float* bk = (const float*)d_in[4];
    const float* Wv = (const float*)d_in[5];
    const float* bv = (const float*)d_in[6];
    const float* Wo = (const float*)d_in[7];
    const float* bo = (const float*)d_in[8];
    float* out = (float*)d_out;

    const size_t XN = (size_t)MM * DD;   // 4,194,304
    const size_t WN = (size_t)DD * DD;   // 1,048,576

    u16* xb  = (u16*)d_ws;
    u16* Wb  = xb  + XN;          // Wq,Wk,Wv stacked: 3*WN
    u16* Wob = Wb  + 3 * WN;
    u16* QKV = Wob + WN;          // Q,K,V stacked: 3*XN
    u16* Yb  = QKV + 3 * XN;
    u16* Op  = Yb  + XN;                         // bf16 [2304][64][128]
    float* Ml = (float*)(Op + (size_t)NSLOT * 8192);  // f32 [2304][2][128]

    cvt_kernel<<<2048, 256, 0, stream>>>(x, xb, (int)(XN / 4));
    cvt4_kernel<<<dim3(256, 4), 256, 0, stream>>>(Wq, Wk, Wv, Wo,
            Wb, Wb + WN, Wb + 2 * WN, Wob, (int)(WN / 4));

    gemm_nt<0><<<dim3(32, 8, 3), 256, 0, stream>>>(xb, Wb, bq, bk, bv,
                                                   QKV, nullptr, MM, DD, DD);
    attn_part<<<NSLOT, 256, 0, stream>>>(QKV, QKV + XN, QKV + 2 * XN, Op, Ml);
    attn_merge<<<512, 256, 0, stream>>>(Op, Ml, Yb);
    gemm_nt<1><<<dim3(32, 8, 1), 256, 0, stream>>>(Yb, Wob, bo, bo, bo,
                                                   nullptr, out, MM, DD, DD);
}

// Round 10
// 132.405 us; speedup vs baseline: 1.4235x; 1.0849x over previous
//
#include <hip/hip_runtime.h>
#include <stdint.h>

// ---------------------------------------------------------------------------
// CausalSelfAttention (B=2, T=2048, D=1024, H=16, Dh=64), fp32 in/out.
// cvt (Wq pre-scaled by 0.125*log2e) -> QKV gemm (V written TRANSPOSED) ->
// flash attn: PASS1 base-free exp2 partials (uniform 256-key chunks, XCD-
// mapped), PASS2 sum-merge -> out gemm.
// ---------------------------------------------------------------------------

typedef unsigned short u16;
typedef __attribute__((ext_vector_type(8)))  __bf16 bf16x8;   // 4 VGPR MFMA A/B frag
typedef __attribute__((ext_vector_type(4)))  float  f32x4;    // 16x16 C/D frag
typedef __attribute__((ext_vector_type(16))) float  f32x16;   // 32x32 C/D frag
typedef __attribute__((ext_vector_type(4)))  float  float4v;
typedef __attribute__((ext_vector_type(4)))  unsigned short u16x4;
typedef __attribute__((ext_vector_type(4)))  unsigned int   u32x4;
typedef __attribute__((ext_vector_type(8)))  short  short8;   // raw 16B load

#define BB 2
#define TT 2048
#define DD 1024
#define HH 16
#define DH 64
#define MM (BB*TT)          // 4096 rows
#define NSLOT 2304          // 32 bh * 72 (qi,chunk) slots
#define CEXP 0.18033688011f // 0.125 * log2(e), folded into Wq/bq

static __device__ __forceinline__ u16 f2bf(float f) {
    uint32_t u = __builtin_bit_cast(uint32_t, f);
    u += 0x7FFFu + ((u >> 16) & 1u);          // round-to-nearest-even
    return (u16)(u >> 16);
}
static __device__ __forceinline__ float bf2f(u16 v) {
    uint32_t u = (uint32_t)v << 16;
    return __builtin_bit_cast(float, u);
}

static __device__ __forceinline__ unsigned cvt_pk_bf16(float a, float b) {
    unsigned r;
    asm("v_cvt_pk_bf16_f32 %0, %1, %2" : "=v"(r) : "v"(a), "v"(b));
    return r;
}

// global(16B per lane) -> LDS direct copy (wave-uniform dst base + lane*16).
static __device__ __forceinline__ void load_lds16(const u16* g, const u16* lds_base) {
    __builtin_amdgcn_global_load_lds(
        (const __attribute__((address_space(1))) void*)(uintptr_t)g,
        (__attribute__((address_space(3)))  void*)(uint32_t)(uintptr_t)lds_base,
        16u, 0, 0u);
}

static __device__ __forceinline__ f32x4 mfma16(bf16x8 a, bf16x8 b, f32x4 c) {
    return __builtin_amdgcn_mfma_f32_16x16x32_bf16(a, b, c, 0, 0, 0);
}
static __device__ __forceinline__ f32x16 mfma32(bf16x8 a, bf16x8 b, f32x16 c) {
    return __builtin_amdgcn_mfma_f32_32x32x16_bf16(a, b, c, 0, 0, 0);
}

// sum of all 16 regs (15-add tree)
static __device__ __forceinline__ float tree_sum16(const f32x16& a) {
    float m[8];
#pragma unroll
    for (int r = 0; r < 8; ++r) m[r] = a[r] + a[r + 8];
#pragma unroll
    for (int off = 4; off; off >>= 1)
#pragma unroll
        for (int r = 0; r < off; ++r) m[r] += m[r + off];
    return m[0];
}

// P regs (8 f32, C-layout key groups) -> one B-operand bf16x8 (T12)
static __device__ __forceinline__ bf16x8 pack8(float s0, float s1, float s2,
        float s3, float s4, float s5, float s6, float s7) {
    unsigned c0 = cvt_pk_bf16(s0, s1);
    unsigned c1 = cvt_pk_bf16(s2, s3);
    unsigned c2 = cvt_pk_bf16(s4, s5);
    unsigned c3 = cvt_pk_bf16(s6, s7);
    asm volatile("v_permlane32_swap_b32 %0, %1" : "+v"(c0), "+v"(c2));
    asm volatile("v_permlane32_swap_b32 %0, %1" : "+v"(c1), "+v"(c3));
    u32x4 w; w[0] = c0; w[1] = c1; w[2] = c2; w[3] = c3;
    return __builtin_bit_cast(bf16x8, w);
}

// ------------------------------ fp32 -> bf16 -------------------------------
__global__ __launch_bounds__(256) void cvt_kernel(const float* __restrict__ src,
                                                  u16* __restrict__ dst, int n4) {
    int i = blockIdx.x * blockDim.x + threadIdx.x;
    int stride = gridDim.x * blockDim.x;
    for (; i < n4; i += stride) {
        float4v v = ((const float4v*)src)[i];
        u16x4 o;
        o[0] = f2bf(v[0]); o[1] = f2bf(v[1]); o[2] = f2bf(v[2]); o[3] = f2bf(v[3]);
        ((u16x4*)dst)[i] = o;
    }
}

// four matrices in one launch; z==0 (Wq) pre-scaled by CEXP
__global__ __launch_bounds__(256) void cvt4_kernel(const float* __restrict__ s0,
        const float* __restrict__ s1, const float* __restrict__ s2,
        const float* __restrict__ s3, u16* __restrict__ d0, u16* __restrict__ d1,
        u16* __restrict__ d2, u16* __restrict__ d3, int n4) {
    const int z = blockIdx.y;
    const float* src = (z == 0) ? s0 : (z == 1) ? s1 : (z == 2) ? s2 : s3;
    u16* dst = (z == 0) ? d0 : (z == 1) ? d1 : (z == 2) ? d2 : d3;
    const float sc = (z == 0) ? CEXP : 1.0f;
    int i = blockIdx.x * blockDim.x + threadIdx.x;
    int stride = gridDim.x * blockDim.x;
    for (; i < n4; i += stride) {
        float4v v = ((const float4v*)src)[i];
        u16x4 o;
        o[0] = f2bf(v[0] * sc); o[1] = f2bf(v[1] * sc);
        o[2] = f2bf(v[2] * sc); o[3] = f2bf(v[3] * sc);
        ((u16x4*)dst)[i] = o;
    }
}

// ------------------------- GEMM  C = A * W^T + bias ------------------------
// A: [M,K] bf16 row-major. W: [z][N,K] bf16 row-major (z = blockIdx.z).
// OUTF32==0: z 0/1 -> bf16 row-major at outb + z*M*N; z==2 -> V TRANSPOSED
// per head: VT[bh=(row>>11)*16+(col>>6)][d=col&63][t=row&2047] at outb+2*M*N.
// OUTF32==1: f32 out to outf. Bias for z==0 scaled by qsc (CEXP fold).
template<int OUTF32>
__global__ __launch_bounds__(256) void gemm_nt(const u16* __restrict__ A,
        const u16* __restrict__ W,
        const float* __restrict__ b0, const float* __restrict__ b1,
        const float* __restrict__ b2, float qsc,
        u16* __restrict__ outb, float* __restrict__ outf,
        int M, int N, int K) {
    __shared__ alignas(16) u16 As[128 * 32];
    __shared__ alignas(16) u16 Bs[128 * 32];

    const int tid  = threadIdx.x;
    const int wave = tid >> 6, lane = tid & 63;
    const int lr = lane & 15, lg = lane >> 4;
    const int wr = wave >> 1, wc = wave & 1;
    const int z  = blockIdx.z;
    const int m0 = blockIdx.x * 128;
    const int n0 = blockIdx.y * 128;

    const u16* Wz = W + (size_t)z * N * K;
    const float* bias = (z == 0) ? b0 : (z == 1) ? b1 : b2;
    const float bsc = (z == 0) ? qsc : 1.0f;

    f32x4 acc[4][4];
#pragma unroll
    for (int m = 0; m < 4; ++m)
#pragma unroll
        for (int n = 0; n < 4; ++n) acc[m][n] = (f32x4){0.f, 0.f, 0.f, 0.f};

    for (int k0 = 0; k0 < K; k0 += 32) {
        __syncthreads();
#pragma unroll
        for (int it = 0; it < 2; ++it) {
            int c = it * 256 + tid;
            int row = c >> 2, cc = (c & 3) * 8;
            const u16* gA = A  + (size_t)(m0 + row) * K + k0 + cc;
            const u16* gB = Wz + (size_t)(n0 + row) * K + k0 + cc;
            load_lds16(gA, As + (size_t)(it * 256 + wave * 64) * 8);
            load_lds16(gB, Bs + (size_t)(it * 256 + wave * 64) * 8);
        }
        __syncthreads();

        bf16x8 af[4], bfm[4];
#pragma unroll
        for (int m = 0; m < 4; ++m)
            af[m] = *(const bf16x8*)&As[(wr * 64 + m * 16 + lr) * 32 + lg * 8];
#pragma unroll
        for (int n = 0; n < 4; ++n)
            bfm[n] = *(const bf16x8*)&Bs[(wc * 64 + n * 16 + lr) * 32 + lg * 8];
#pragma unroll
        for (int m = 0; m < 4; ++m)
#pragma unroll
            for (int n = 0; n < 4; ++n)
                acc[m][n] = mfma16(af[m], bfm[n], acc[m][n]);
    }

#pragma unroll
    for (int n = 0; n < 4; ++n) {
        int col = n0 + wc * 64 + n * 16 + lr;
        float bv = bias[col] * bsc;
#pragma unroll
        for (int m = 0; m < 4; ++m) {
            int row = m0 + wr * 64 + m * 16 + lg * 4;
            if (OUTF32 == 0 && z == 2) {
                // V transposed: VT[bh][d][t], 4 consecutive t per store
                u16* vt = outb + (size_t)2 * M * N;
                size_t base = ((size_t)(((row >> 11) * 16 + (col >> 6)) * 64
                                        + (col & 63))) * 2048 + (row & 2047);
                u16x4 pv;
#pragma unroll
                for (int r = 0; r < 4; ++r) pv[r] = f2bf(acc[m][n][r] + bv);
                *(u16x4*)&vt[base] = pv;
            } else {
#pragma unroll
                for (int r = 0; r < 4; ++r) {
                    float v = acc[m][n][r] + bv;
                    if (OUTF32 == 0)
                        outb[(size_t)z * M * N + (size_t)(row + r) * N + col] = f2bf(v);
                    else
                        outf[(size_t)(row + r) * N + col] = v;
                }
            }
        }
    }
}

// --------------------------- attention pass 1 ------------------------------
// KV-split flash partials, base-free softmax: p = exp2(st) directly (Q was
// pre-scaled by CEXP; no max tracking -- O and l scale together, O/l exact).
// Grid 2304 XCD-mapped: block i -> bh = (i&7)*4 + (i>>3)/72, s = (i>>3)%72.
// s -> (qi 0..15, ch); chunk = 256 keys; 4 warps x 32 q = 128 q rows.
// K and V^T both staged via global_load_lds (V pre-transposed by the GEMM).
// nc==1 (qi<2): normalize and write Y directly; else partials Op/Ml.
__global__ __launch_bounds__(256) void attn_part(const u16* __restrict__ Qb,
        const u16* __restrict__ Kb, const u16* __restrict__ VTb,
        u16* __restrict__ Op, float* __restrict__ Ml, u16* __restrict__ Yb) {
    __shared__ alignas(16) u16 Ks[64 * 64];   // [key][d], XOR-swizzled 16B slots
    __shared__ alignas(16) u16 Vs[64 * 64];   // [d][key], XOR-swizzled 16B slots

    const int tid  = threadIdx.x;
    const int wave = tid >> 6, lane = tid & 63;
    const int lq = lane & 31, hi = lane >> 5;

    const int i0 = blockIdx.x;
    const int bh = (i0 & 7) * 4 + ((i0 >> 3) / 72);
    const int s  = (i0 >> 3) % 72;
    int qi = 0, ch = 0;
    {
        int cum = 0, found = 0;
#pragma unroll
        for (int j = 0; j < 16; ++j) {
            int n = (j + 2) >> 1;
            if (!found && s < cum + n) { qi = j; ch = s - cum; found = 1; }
            cum += n;
        }
    }
    const int nc = (qi + 2) >> 1;
    const int b = bh >> 4, h = bh & 15;
    const size_t rb = (size_t)b * TT;
    const int hoff = h * DH;
    const int q0w = qi * 128 + wave * 32;     // warp q base
    const int k0 = ch * 256;
    const int kend = qi * 128 + 128;
    const int k1 = (k0 + 256 < kend) ? k0 + 256 : kend;

    // staging coords: chunk c = it*256+tid -> row=c>>3, slot=c&7
    const int srow0 = tid >> 3, sl = tid & 7;
    const int srow1 = (256 + tid) >> 3;

    const u16* Kbh = Kb + rb * DD + hoff;
    const u16* Vbh = VTb + (size_t)bh * 64 * 2048;

    // Q fragments (B-operand): col=lane&31=q, k=(lane>>5)*8+j ; 4 chunks of 16
    bf16x8 qf[4];
    {
        const u16* qrow = Qb + (rb + q0w + lq) * DD + hoff + hi * 8;
#pragma unroll
        for (int kc = 0; kc < 4; ++kc) qf[kc] = *(const bf16x8*)(qrow + kc * 16);
    }

    f32x16 o0 = {}, o1 = {};
    float l_i = 0.f;

    for (int kv0 = k0; kv0 < k1; kv0 += 64) {
        __syncthreads();
        // K tile [64 key][64 d] and V^T tile [64 d][64 key], swizzled source
        load_lds16(Kbh + (size_t)(kv0 + srow0) * DD + (sl ^ (srow0 & 7)) * 8,
                   &Ks[(size_t)(wave * 64) * 8]);
        load_lds16(Kbh + (size_t)(kv0 + srow1) * DD + (sl ^ (srow1 & 7)) * 8,
                   &Ks[(size_t)(256 + wave * 64) * 8]);
        load_lds16(Vbh + (size_t)srow0 * 2048 + kv0 + (sl ^ (srow0 & 7)) * 8,
                   &Vs[(size_t)(wave * 64) * 8]);
        load_lds16(Vbh + (size_t)srow1 * 2048 + kv0 + (sl ^ (srow1 & 7)) * 8,
                   &Vs[(size_t)(256 + wave * 64) * 8]);
        __syncthreads();

        if (kv0 < q0w + 32) {
            const int rowm = lq & 7;
            const bool diag = (kv0 + 63 > q0w);
            const int qrel = q0w + lq - kv0;
            bf16x8 pb[4];

            // ---- keys 0..31
            {
                f32x16 st = {};
#pragma unroll
                for (int kc = 0; kc < 4; ++kc) {
                    bf16x8 kf = *(const bf16x8*)&Ks[lq * 64 + ((2 * kc + hi) ^ rowm) * 8];
                    st = mfma32(kf, qf[kc], st);
                }
                if (diag) {
#pragma unroll
                    for (int r = 0; r < 16; ++r) {
                        int key = (r & 3) + 8 * (r >> 2) + 4 * hi;
                        if (key > qrel) st[r] = -1e30f;
                    }
                }
#pragma unroll
                for (int r = 0; r < 16; ++r) st[r] = __builtin_amdgcn_exp2f(st[r]);
                l_i += tree_sum16(st);
                pb[0] = pack8(st[0], st[1], st[2], st[3], st[4], st[5], st[6], st[7]);
                pb[1] = pack8(st[8], st[9], st[10], st[11], st[12], st[13], st[14], st[15]);
            }
            // ---- keys 32..63
            {
                f32x16 st = {};
#pragma unroll
                for (int kc = 0; kc < 4; ++kc) {
                    bf16x8 kf = *(const bf16x8*)&Ks[(32 + lq) * 64 + ((2 * kc + hi) ^ rowm) * 8];
                    st = mfma32(kf, qf[kc], st);
                }
                if (diag) {
#pragma unroll
                    for (int r = 0; r < 16; ++r) {
                        int key = 32 + (r & 3) + 8 * (r >> 2) + 4 * hi;
                        if (key > qrel) st[r] = -1e30f;
                    }
                }
#pragma unroll
                for (int r = 0; r < 16; ++r) st[r] = __builtin_amdgcn_exp2f(st[r]);
                l_i += tree_sum16(st);
                pb[2] = pack8(st[0], st[1], st[2], st[3], st[4], st[5], st[6], st[7]);
                pb[3] = pack8(st[8], st[9], st[10], st[11], st[12], st[13], st[14], st[15]);
            }

            // O^T += V^T . P^T : A=V^T (row=d, swizzled read), B=P^T (col=q)
#pragma unroll
            for (int ks = 0; ks < 4; ++ks) {
                bf16x8 vf0 = *(const bf16x8*)&Vs[lq * 64        + ((ks * 2 + hi) ^ rowm) * 8];
                bf16x8 vf1 = *(const bf16x8*)&Vs[(32 + lq) * 64 + ((ks * 2 + hi) ^ rowm) * 8];
                o0 = mfma32(vf0, pb[ks], o0);
                o1 = mfma32(vf1, pb[ks], o1);
            }
        }
    }

    l_i += __shfl_xor(l_i, 32);
    const int col = wave * 32 + lq;

    if (nc == 1) {
        // single chunk: normalize and write Y directly
        const float inv = 1.0f / l_i;
        u16* yrow = Yb + (rb + q0w + lq) * DD + hoff;
#pragma unroll
        for (int g = 0; g < 4; ++g) {
            u16x4 p0, p1;
#pragma unroll
            for (int j = 0; j < 4; ++j) {
                p0[j] = f2bf(o0[4 * g + j] * inv);
                p1[j] = f2bf(o1[4 * g + j] * inv);
            }
            *(u16x4*)&yrow[8 * g + 4 * hi]      = p0;
            *(u16x4*)&yrow[32 + 8 * g + 4 * hi] = p1;
        }
    } else {
        const int slot = bh * 72 + s;
        u16* op = Op + (size_t)slot * 8192;
#pragma unroll
        for (int r = 0; r < 16; ++r) {
            const int d0 = (r & 3) + 8 * (r >> 2) + 4 * hi;
            op[d0 * 128 + col]        = f2bf(o0[r]);
            op[(32 + d0) * 128 + col] = f2bf(o1[r]);
        }
        if (hi == 0) Ml[(size_t)slot * 128 + col] = l_i;
    }
}

// --------------------------- attention pass 2 ------------------------------
// grid 512 = 32 bh x 16 qi; 256 thr. qi<2 handled by pass1 (early return).
// No max bookkeeping: O = sum_c O_c / sum_c l_c (common exp2 base).
__global__ __launch_bounds__(256) void attn_merge(const u16* __restrict__ Op,
        const float* __restrict__ Ml, u16* __restrict__ Yb) {
    const int bq = blockIdx.x;
    const int bh = bq >> 4, qi = bq & 15;
    const int nc = (qi + 2) >> 1;
    if (nc == 1) return;
    int cum = 0;
#pragma unroll
    for (int j = 0; j < 16; ++j) cum += (j < qi) ? ((j + 2) >> 1) : 0;
    const int s0 = bh * 72 + cum;

    const int t = threadIdx.x;
    const int row = t >> 1, dh = (t & 1) * 32;

    float L = 0.f;
    float acc[32];
#pragma unroll
    for (int d = 0; d < 32; ++d) acc[d] = 0.f;
#pragma unroll
    for (int c = 0; c < 8; ++c) {
        if (c < nc) {
            L += Ml[(size_t)(s0 + c) * 128 + row];
            const u16* op = Op + (size_t)(s0 + c) * 8192 + row;
#pragma unroll
            for (int d = 0; d < 32; ++d)
                acc[d] += bf2f(op[(dh + d) * 128]);
        }
    }
    const float inv = 1.0f / L;

    const int b = bh >> 4, h = bh & 15;
    u16* yrow = Yb + ((size_t)(b * TT + qi * 128 + row)) * DD + h * DH + dh;
#pragma unroll
    for (int g = 0; g < 8; ++g) {
        u16x4 p;
#pragma unroll
        for (int j = 0; j < 4; ++j) p[j] = f2bf(acc[4 * g + j] * inv);
        *(u16x4*)&yrow[4 * g] = p;
    }
}

// ------------------------------- launcher ----------------------------------
extern "C" void kernel_launch(void* const* d_in, const int* in_sizes, int n_in,
                              void* d_out, int out_size, void* d_ws, size_t ws_size,
                              hipStream_t stream) {
    const float* x  = (const float*)d_in[0];
    const float* Wq = (const float*)d_in[1];
    const float* bq = (const float*)d_in[2];
    const float* Wk = (const float*)d_in[3];
    const float* bk = (const float*)d_in[4];
    const float* Wv = (const float*)d_in[5];
    const float* bv = (const float*)d_in[6];
    const float* Wo = (const float*)d_in[7];
    const float* bo = (const float*)d_in[8];
    float* out = (float*)d_out;

    const size_t XN = (size_t)MM * DD;   // 4,194,304
    const size_t WN = (size_t)DD * DD;   // 1,048,576

    u16* xb  = (u16*)d_ws;
    u16* Wb  = xb  + XN;          // Wq,Wk,Wv stacked: 3*WN
    u16* Wob = Wb  + 3 * WN;
    u16* QKV = Wob + WN;          // Q, K, VT stacked: 3*XN
    u16* Yb  = QKV + 3 * XN;
    u16* Op  = Yb  + XN;                              // bf16 [2304][64][128]
    float* Ml = (float*)(Op + (size_t)NSLOT * 8192);  // f32 [2304][128]

    cvt_kernel<<<2048, 256, 0, stream>>>(x, xb, (int)(XN / 4));
    cvt4_kernel<<<dim3(256, 4), 256, 0, stream>>>(Wq, Wk, Wv, Wo,
            Wb, Wb + WN, Wb + 2 * WN, Wob, (int)(WN / 4));

    gemm_nt<0><<<dim3(32, 8, 3), 256, 0, stream>>>(xb, Wb, bq, bk, bv, CEXP,
                                                   QKV, nullptr, MM, DD, DD);
    attn_part<<<NSLOT, 256, 0, stream>>>(QKV, QKV + XN, QKV + 2 * XN,
                                         Op, Ml, Yb);
    attn_merge<<<512, 256, 0, stream>>>(Op, Ml, Yb);
    gemm_nt<1><<<dim3(32, 8, 1), 256, 0, stream>>>(Yb, Wob, bo, bo, bo, 1.0f,
                                                   nullptr, out, MM, DD, DD);
}

// Round 11
// 120.256 us; speedup vs baseline: 1.5674x; 1.1010x over previous
//
#include <hip/hip_runtime.h>
#include <stdint.h>

// ---------------------------------------------------------------------------
// CausalSelfAttention (B=2, T=2048, D=1024, H=16, Dh=64), fp32 in/out.
// cvt (Wq pre-scaled) -> fused {Q,K proj + V^T} gemm (dbuf, 1-barrier/K-step)
// -> flash attn KV-split (512-key chunks, dbuf, setprio) -> merge -> out gemm.
// ---------------------------------------------------------------------------

typedef unsigned short u16;
typedef __attribute__((ext_vector_type(8)))  __bf16 bf16x8;   // 4 VGPR MFMA A/B frag
typedef __attribute__((ext_vector_type(4)))  float  f32x4;    // 16x16 C/D frag
typedef __attribute__((ext_vector_type(16))) float  f32x16;   // 32x32 C/D frag
typedef __attribute__((ext_vector_type(4)))  float  float4v;
typedef __attribute__((ext_vector_type(4)))  unsigned short u16x4;
typedef __attribute__((ext_vector_type(4)))  unsigned int   u32x4;
typedef __attribute__((ext_vector_type(8)))  short  short8;   // raw 16B load

#define BB 2
#define TT 2048
#define DD 1024
#define HH 16
#define DH 64
#define MM (BB*TT)          // 4096 rows
#define NSLOT 1280          // 32 bh * 40 (qi,chunk) slots (512-key chunks)
#define CEXP 0.18033688011f // 0.125 * log2(e), folded into Wq/bq
#define XNE ((size_t)MM*DD)
#define WNE ((size_t)DD*DD)

static __device__ __forceinline__ u16 f2bf(float f) {
    uint32_t u = __builtin_bit_cast(uint32_t, f);
    u += 0x7FFFu + ((u >> 16) & 1u);          // round-to-nearest-even
    return (u16)(u >> 16);
}
static __device__ __forceinline__ float bf2f(u16 v) {
    uint32_t u = (uint32_t)v << 16;
    return __builtin_bit_cast(float, u);
}

static __device__ __forceinline__ unsigned cvt_pk_bf16(float a, float b) {
    unsigned r;
    asm("v_cvt_pk_bf16_f32 %0, %1, %2" : "=v"(r) : "v"(a), "v"(b));
    return r;
}

// global(16B per lane) -> LDS direct copy (wave-uniform dst base + lane*16).
static __device__ __forceinline__ void load_lds16(const u16* g, const u16* lds_base) {
    __builtin_amdgcn_global_load_lds(
        (const __attribute__((address_space(1))) void*)(uintptr_t)g,
        (__attribute__((address_space(3)))  void*)(uint32_t)(uintptr_t)lds_base,
        16u, 0, 0u);
}

static __device__ __forceinline__ f32x4 mfma16(bf16x8 a, bf16x8 b, f32x4 c) {
    return __builtin_amdgcn_mfma_f32_16x16x32_bf16(a, b, c, 0, 0, 0);
}
static __device__ __forceinline__ f32x16 mfma32(bf16x8 a, bf16x8 b, f32x16 c) {
    return __builtin_amdgcn_mfma_f32_32x32x16_bf16(a, b, c, 0, 0, 0);
}

// sum of all 16 regs (15-add tree)
static __device__ __forceinline__ float tree_sum16(const f32x16& a) {
    float m[8];
#pragma unroll
    for (int r = 0; r < 8; ++r) m[r] = a[r] + a[r + 8];
#pragma unroll
    for (int off = 4; off; off >>= 1)
#pragma unroll
        for (int r = 0; r < off; ++r) m[r] += m[r + off];
    return m[0];
}

// P regs (8 f32, C-layout key groups) -> one B-operand bf16x8 (T12)
static __device__ __forceinline__ bf16x8 pack8(float s0, float s1, float s2,
        float s3, float s4, float s5, float s6, float s7) {
    unsigned c0 = cvt_pk_bf16(s0, s1);
    unsigned c1 = cvt_pk_bf16(s2, s3);
    unsigned c2 = cvt_pk_bf16(s4, s5);
    unsigned c3 = cvt_pk_bf16(s6, s7);
    asm volatile("v_permlane32_swap_b32 %0, %1" : "+v"(c0), "+v"(c2));
    asm volatile("v_permlane32_swap_b32 %0, %1" : "+v"(c1), "+v"(c3));
    u32x4 w; w[0] = c0; w[1] = c1; w[2] = c2; w[3] = c3;
    return __builtin_bit_cast(bf16x8, w);
}

// ------------------------------ fp32 -> bf16 -------------------------------
__global__ __launch_bounds__(256) void cvt_kernel(const float* __restrict__ src,
                                                  u16* __restrict__ dst, int n4) {
    int i = blockIdx.x * blockDim.x + threadIdx.x;
    int stride = gridDim.x * blockDim.x;
    for (; i < n4; i += stride) {
        float4v v = ((const float4v*)src)[i];
        u16x4 o;
        o[0] = f2bf(v[0]); o[1] = f2bf(v[1]); o[2] = f2bf(v[2]); o[3] = f2bf(v[3]);
        ((u16x4*)dst)[i] = o;
    }
}

// four matrices in one launch; z==0 (Wq) pre-scaled by CEXP
__global__ __launch_bounds__(256) void cvt4_kernel(const float* __restrict__ s0,
        const float* __restrict__ s1, const float* __restrict__ s2,
        const float* __restrict__ s3, u16* __restrict__ d0, u16* __restrict__ d1,
        u16* __restrict__ d2, u16* __restrict__ d3, int n4) {
    const int z = blockIdx.y;
    const float* src = (z == 0) ? s0 : (z == 1) ? s1 : (z == 2) ? s2 : s3;
    u16* dst = (z == 0) ? d0 : (z == 1) ? d1 : (z == 2) ? d2 : d3;
    const float sc = (z == 0) ? CEXP : 1.0f;
    int i = blockIdx.x * blockDim.x + threadIdx.x;
    int stride = gridDim.x * blockDim.x;
    for (; i < n4; i += stride) {
        float4v v = ((const float4v*)src)[i];
        u16x4 o;
        o[0] = f2bf(v[0] * sc); o[1] = f2bf(v[1] * sc);
        o[2] = f2bf(v[2] * sc); o[3] = f2bf(v[3] * sc);
        ((u16x4*)dst)[i] = o;
    }
}

// ----------------- GEMM, dbuf + single barrier per K-step ------------------
// 128x128 tile, BK=32, K=1024, 256 thr (4 waves 2x2). T3-minimum pipeline:
// stage(next) issued BEFORE compute(cur); one __syncthreads per K-step
// (its vmcnt/lgkm drain publishes the prefetch).
// MODE 0 (fused, grid 768): id<512 -> z=id>>8 Q/K proj (col-bias, bf16 out,
//   Wq path pre-scaled); id>=512 -> V^T gemm: C = Wv . x_b^T (row-bias bv),
//   out row-major [1024 hd][2048 t] at vt + b*1024*2048 (coalesced in t).
// MODE 1 (grid 256): out-proj, f32 out + col-bias.
template<int MODE>
__global__ __launch_bounds__(256) void gemm2(const u16* __restrict__ xb,
        const u16* __restrict__ Wb, const float* __restrict__ bq,
        const float* __restrict__ bk, const float* __restrict__ bvv,
        u16* __restrict__ outq, u16* __restrict__ vt, float* __restrict__ outf) {
    __shared__ alignas(16) u16 As[2][128 * 32];
    __shared__ alignas(16) u16 Bs[2][128 * 32];

    const int tid  = threadIdx.x;
    const int wave = tid >> 6, lane = tid & 63;
    const int lr = lane & 15, lg = lane >> 4;
    const int wr = wave >> 1, wc = wave & 1;
    const int K = 1024;

    const u16 *Ap, *Wp;
    int m0, n0, zb = 0;
    bool vtmode = false;
    const int id = blockIdx.x;
    if (MODE == 0) {
        if (id < 512) {
            zb = id >> 8; int r = id & 255;
            m0 = (r >> 3) * 128; n0 = (r & 7) * 128;
            Ap = xb; Wp = Wb + (size_t)zb * WNE;
        } else {
            int v = id - 512; zb = v >> 7; int r = v & 127;
            m0 = (r >> 4) * 128; n0 = (r & 15) * 128;
            Ap = Wb + 2 * WNE;                       // Wv
            Wp = xb + (size_t)zb * 2048 * 1024;      // x_b
            vtmode = true;
        }
    } else {
        m0 = (id >> 3) * 128; n0 = (id & 7) * 128;
        Ap = xb; Wp = Wb;
    }

    f32x4 acc[4][4];
#pragma unroll
    for (int m = 0; m < 4; ++m)
#pragma unroll
        for (int n = 0; n < 4; ++n) acc[m][n] = (f32x4){0.f, 0.f, 0.f, 0.f};

#define G_STAGE(BB_, KK_)                                                     \
    {                                                                         \
        _Pragma("unroll")                                                     \
        for (int it = 0; it < 2; ++it) {                                      \
            int c = it * 256 + tid;                                           \
            int row = c >> 2, cc = (c & 3) * 8;                               \
            load_lds16(Ap + (size_t)(m0 + row) * K + (KK_) + cc,              \
                       &As[BB_][(size_t)(it * 256 + wave * 64) * 8]);         \
            load_lds16(Wp + (size_t)(n0 + row) * K + (KK_) + cc,              \
                       &Bs[BB_][(size_t)(it * 256 + wave * 64) * 8]);         \
        }                                                                     \
    }

    G_STAGE(0, 0);
    __syncthreads();
    int cur = 0;
    for (int k0 = 0; k0 < K; k0 += 32) {
        if (k0 + 32 < K) G_STAGE(cur ^ 1, k0 + 32);

        bf16x8 af[4], bfm[4];
#pragma unroll
        for (int m = 0; m < 4; ++m)
            af[m] = *(const bf16x8*)&As[cur][(wr * 64 + m * 16 + lr) * 32 + lg * 8];
#pragma unroll
        for (int n = 0; n < 4; ++n)
            bfm[n] = *(const bf16x8*)&Bs[cur][(wc * 64 + n * 16 + lr) * 32 + lg * 8];
#pragma unroll
        for (int m = 0; m < 4; ++m)
#pragma unroll
            for (int n = 0; n < 4; ++n)
                acc[m][n] = mfma16(af[m], bfm[n], acc[m][n]);

        __syncthreads();   // drains vmcnt: next buffer published
        cur ^= 1;
    }
#undef G_STAGE

    if (MODE == 1) {
#pragma unroll
        for (int n = 0; n < 4; ++n) {
            int col = n0 + wc * 64 + n * 16 + lr;
            float bvl = bq[col];
#pragma unroll
            for (int m = 0; m < 4; ++m) {
                int row = m0 + wr * 64 + m * 16 + lg * 4;
#pragma unroll
                for (int r = 0; r < 4; ++r)
                    outf[(size_t)(row + r) * 1024 + col] = acc[m][n][r] + bvl;
            }
        }
    } else if (!vtmode) {
        const float* bias = zb ? bk : bq;
        const float bsc = zb ? 1.0f : CEXP;
#pragma unroll
        for (int n = 0; n < 4; ++n) {
            int col = n0 + wc * 64 + n * 16 + lr;
            float bvl = bias[col] * bsc;
#pragma unroll
            for (int m = 0; m < 4; ++m) {
                int row = m0 + wr * 64 + m * 16 + lg * 4;
#pragma unroll
                for (int r = 0; r < 4; ++r)
                    outq[(size_t)zb * XNE + (size_t)(row + r) * 1024 + col] =
                        f2bf(acc[m][n][r] + bvl);
            }
        }
    } else {
        // V^T: rows = hd (row-bias), cols = t (coalesced)
        u16* vo = vt + (size_t)zb * 1024 * 2048;
#pragma unroll
        for (int m = 0; m < 4; ++m) {
            int rowb = m0 + wr * 64 + m * 16 + lg * 4;
            float bvr[4];
#pragma unroll
            for (int r = 0; r < 4; ++r) bvr[r] = bvv[rowb + r];
#pragma unroll
            for (int n = 0; n < 4; ++n) {
                int col = n0 + wc * 64 + n * 16 + lr;
#pragma unroll
                for (int r = 0; r < 4; ++r)
                    vo[(size_t)(rowb + r) * 2048 + col] = f2bf(acc[m][n][r] + bvr[r]);
            }
        }
    }
}

// --------------------------- attention pass 1 ------------------------------
// KV-split flash partials, base-free exp2 softmax (Q pre-scaled by CEXP).
// 512-key chunks: slot s -> (qi, ch) with nch(qi) = (qi>>2)+1 (40 slots/bh).
// Grid 1280 XCD-mapped: i -> bh=(i&7)*4+(i>>3)/40, s=(i>>3)%40.
// KV double-buffered; stage(next) issued before compute(cur); ONE barrier
// per tile. setprio(1) around MFMA clusters (T5, attn-positive m191).
// nc==1 (qi<4): normalize + write Y directly; else partials Op/Ml.
__global__ __launch_bounds__(256) void attn_part(const u16* __restrict__ Qb,
        const u16* __restrict__ Kb, const u16* __restrict__ VTb,
        u16* __restrict__ Op, float* __restrict__ Ml, u16* __restrict__ Yb) {
    __shared__ alignas(16) u16 Ks[2][64 * 64];   // [key][d], swizzled 16B slots
    __shared__ alignas(16) u16 Vs[2][64 * 64];   // [d][key], swizzled 16B slots

    const int tid  = threadIdx.x;
    const int wave = tid >> 6, lane = tid & 63;
    const int lq = lane & 31, hi = lane >> 5;

    const int i0 = blockIdx.x;
    const int bh = (i0 & 7) * 4 + ((i0 >> 3) / 40);
    const int s  = (i0 >> 3) % 40;
    int qi = 0, ch = 0;
    {
        int cum = 0, found = 0;
#pragma unroll
        for (int j = 0; j < 16; ++j) {
            int n = (j >> 2) + 1;
            if (!found && s < cum + n) { qi = j; ch = s - cum; found = 1; }
            cum += n;
        }
    }
    const int nc = (qi >> 2) + 1;
    const int b = bh >> 4, h = bh & 15;
    const size_t rb = (size_t)b * TT;
    const int hoff = h * DH;
    const int q0w = qi * 128 + wave * 32;     // warp q base
    const int k0 = ch * 512;
    const int kend = qi * 128 + 128;
    const int k1 = (k0 + 512 < kend) ? k0 + 512 : kend;

    // staging coords: chunk c = it*256+tid -> row=c>>3, slot=c&7
    const int srow0 = tid >> 3, sl = tid & 7;
    const int srow1 = (256 + tid) >> 3;

    const u16* Kbh = Kb + rb * DD + hoff;
    const u16* Vbh = VTb + (size_t)bh * 64 * 2048;

    // Q fragments (B-operand): col=lane&31=q, k=(lane>>5)*8+j ; 4 chunks of 16
    bf16x8 qf[4];
    {
        const u16* qrow = Qb + (rb + q0w + lq) * DD + hoff + hi * 8;
#pragma unroll
        for (int kc = 0; kc < 4; ++kc) qf[kc] = *(const bf16x8*)(qrow + kc * 16);
    }

    f32x16 o0 = {}, o1 = {};
    float l_i = 0.f;

#define A_STAGE(BB_, KV_)                                                     \
    {                                                                         \
        load_lds16(Kbh + (size_t)((KV_) + srow0) * DD + (sl ^ (srow0 & 7)) * 8,\
                   &Ks[BB_][(size_t)(wave * 64) * 8]);                        \
        load_lds16(Kbh + (size_t)((KV_) + srow1) * DD + (sl ^ (srow1 & 7)) * 8,\
                   &Ks[BB_][(size_t)(256 + wave * 64) * 8]);                  \
        load_lds16(Vbh + (size_t)srow0 * 2048 + (KV_) + (sl ^ (srow0 & 7)) * 8,\
                   &Vs[BB_][(size_t)(wave * 64) * 8]);                        \
        load_lds16(Vbh + (size_t)srow1 * 2048 + (KV_) + (sl ^ (srow1 & 7)) * 8,\
                   &Vs[BB_][(size_t)(256 + wave * 64) * 8]);                  \
    }

    A_STAGE(0, k0);
    __syncthreads();
    int cur = 0;

    for (int kv0 = k0; kv0 < k1; kv0 += 64) {
        if (kv0 + 64 < k1) A_STAGE(cur ^ 1, kv0 + 64);

        if (kv0 < q0w + 32) {
            const int rowm = lq & 7;
            const bool diag = (kv0 + 63 > q0w);
            const int qrel = q0w + lq - kv0;
            bf16x8 pb[4];

            // ---- keys 0..31
            {
                f32x16 st = {};
                __builtin_amdgcn_s_setprio(1);
#pragma unroll
                for (int kc = 0; kc < 4; ++kc) {
                    bf16x8 kf = *(const bf16x8*)&Ks[cur][lq * 64 + ((2 * kc + hi) ^ rowm) * 8];
                    st = mfma32(kf, qf[kc], st);
                }
                __builtin_amdgcn_s_setprio(0);
                if (diag) {
#pragma unroll
                    for (int r = 0; r < 16; ++r) {
                        int key = (r & 3) + 8 * (r >> 2) + 4 * hi;
                        if (key > qrel) st[r] = -1e30f;
                    }
                }
#pragma unroll
                for (int r = 0; r < 16; ++r) st[r] = __builtin_amdgcn_exp2f(st[r]);
                l_i += tree_sum16(st);
                pb[0] = pack8(st[0], st[1], st[2], st[3], st[4], st[5], st[6], st[7]);
                pb[1] = pack8(st[8], st[9], st[10], st[11], st[12], st[13], st[14], st[15]);
            }
            // ---- keys 32..63
            {
                f32x16 st = {};
                __builtin_amdgcn_s_setprio(1);
#pragma unroll
                for (int kc = 0; kc < 4; ++kc) {
                    bf16x8 kf = *(const bf16x8*)&Ks[cur][(32 + lq) * 64 + ((2 * kc + hi) ^ rowm) * 8];
                    st = mfma32(kf, qf[kc], st);
                }
                __builtin_amdgcn_s_setprio(0);
                if (diag) {
#pragma unroll
                    for (int r = 0; r < 16; ++r) {
                        int key = 32 + (r & 3) + 8 * (r >> 2) + 4 * hi;
                        if (key > qrel) st[r] = -1e30f;
                    }
                }
#pragma unroll
                for (int r = 0; r < 16; ++r) st[r] = __builtin_amdgcn_exp2f(st[r]);
                l_i += tree_sum16(st);
                pb[2] = pack8(st[0], st[1], st[2], st[3], st[4], st[5], st[6], st[7]);
                pb[3] = pack8(st[8], st[9], st[10], st[11], st[12], st[13], st[14], st[15]);
            }

            // O^T += V^T . P^T
            __builtin_amdgcn_s_setprio(1);
#pragma unroll
            for (int ks = 0; ks < 4; ++ks) {
                bf16x8 vf0 = *(const bf16x8*)&Vs[cur][lq * 64        + ((ks * 2 + hi) ^ rowm) * 8];
                bf16x8 vf1 = *(const bf16x8*)&Vs[cur][(32 + lq) * 64 + ((ks * 2 + hi) ^ rowm) * 8];
                o0 = mfma32(vf0, pb[ks], o0);
                o1 = mfma32(vf1, pb[ks], o1);
            }
            __builtin_amdgcn_s_setprio(0);
        }

        __syncthreads();   // drains vmcnt: next KV buffer published
        cur ^= 1;
    }
#undef A_STAGE

    l_i += __shfl_xor(l_i, 32);
    const int col = wave * 32 + lq;

    if (nc == 1) {
        const float inv = 1.0f / l_i;
        u16* yrow = Yb + (rb + q0w + lq) * DD + hoff;
#pragma unroll
        for (int g = 0; g < 4; ++g) {
            u16x4 p0, p1;
#pragma unroll
            for (int j = 0; j < 4; ++j) {
                p0[j] = f2bf(o0[4 * g + j] * inv);
                p1[j] = f2bf(o1[4 * g + j] * inv);
            }
            *(u16x4*)&yrow[8 * g + 4 * hi]      = p0;
            *(u16x4*)&yrow[32 + 8 * g + 4 * hi] = p1;
        }
    } else {
        const int slot = bh * 40 + s;
        u16* op = Op + (size_t)slot * 8192;
#pragma unroll
        for (int r = 0; r < 16; ++r) {
            const int d0 = (r & 3) + 8 * (r >> 2) + 4 * hi;
            op[d0 * 128 + col]        = f2bf(o0[r]);
            op[(32 + d0) * 128 + col] = f2bf(o1[r]);
        }
        if (hi == 0) Ml[(size_t)slot * 128 + col] = l_i;
    }
}

// --------------------------- attention pass 2 ------------------------------
// grid 512 = 32 bh x 16 qi; 256 thr. qi<4 handled by pass1 (early return).
// O = sum_c O_c / sum_c l_c (common exp2 base, no max bookkeeping).
__global__ __launch_bounds__(256) void attn_merge(const u16* __restrict__ Op,
        const float* __restrict__ Ml, u16* __restrict__ Yb) {
    const int bq = blockIdx.x;
    const int bh = bq >> 4, qi = bq & 15;
    const int nc = (qi >> 2) + 1;
    if (nc == 1) return;
    int cum = 0;
#pragma unroll
    for (int j = 0; j < 16; ++j) cum += (j < qi) ? ((j >> 2) + 1) : 0;
    const int s0 = bh * 40 + cum;

    const int t = threadIdx.x;
    const int row = t >> 1, dh = (t & 1) * 32;

    float L = 0.f;
    float acc[32];
#pragma unroll
    for (int d = 0; d < 32; ++d) acc[d] = 0.f;
#pragma unroll
    for (int c = 0; c < 4; ++c) {
        if (c < nc) {
            L += Ml[(size_t)(s0 + c) * 128 + row];
            const u16* op = Op + (size_t)(s0 + c) * 8192 + row;
#pragma unroll
            for (int d = 0; d < 32; ++d)
                acc[d] += bf2f(op[(dh + d) * 128]);
        }
    }
    const float inv = 1.0f / L;

    const int b = bh >> 4, h = bh & 15;
    u16* yrow = Yb + ((size_t)(b * TT + qi * 128 + row)) * DD + h * DH + dh;
#pragma unroll
    for (int g = 0; g < 8; ++g) {
        u16x4 p;
#pragma unroll
        for (int j = 0; j < 4; ++j) p[j] = f2bf(acc[4 * g + j] * inv);
        *(u16x4*)&yrow[4 * g] = p;
    }
}

// ------------------------------- launcher ----------------------------------
extern "C" void kernel_launch(void* const* d_in, const int* in_sizes, int n_in,
                              void* d_out, int out_size, void* d_ws, size_t ws_size,
                              hipStream_t stream) {
    const float* x  = (const float*)d_in[0];
    const float* Wq = (const float*)d_in[1];
    const float* bq = (const float*)d_in[2];
    const float* Wk = (const float*)d_in[3];
    const float* bk = (const float*)d_in[4];
    const float* Wv = (const float*)d_in[5];
    const float* bv = (const float*)d_in[6];
    const float* Wo = (const float*)d_in[7];
    const float* bo = (const float*)d_in[8];
    float* out = (float*)d_out;

    u16* xb  = (u16*)d_ws;
    u16* Wb  = xb  + XNE;         // Wq,Wk,Wv stacked: 3*WNE
    u16* Wob = Wb  + 3 * WNE;
    u16* QKV = Wob + WNE;         // Q, K, VT stacked: 3*XNE
    u16* Yb  = QKV + 3 * XNE;
    u16* Op  = Yb  + XNE;                             // bf16 [1280][64][128]
    float* Ml = (float*)(Op + (size_t)NSLOT * 8192);  // f32 [1280][128]

    cvt_kernel<<<2048, 256, 0, stream>>>(x, xb, (int)(XNE / 4));
    cvt4_kernel<<<dim3(256, 4), 256, 0, stream>>>(Wq, Wk, Wv, Wo,
            Wb, Wb + WNE, Wb + 2 * WNE, Wob, (int)(WNE / 4));

    // fused Q-proj, K-proj, V^T gemm (768 blocks)
    gemm2<0><<<768, 256, 0, stream>>>(xb, Wb, bq, bk, bv,
                                      QKV, QKV + 2 * XNE, nullptr);
    attn_part<<<NSLOT, 256, 0, stream>>>(QKV, QKV + XNE, QKV + 2 * XNE,
                                         Op, Ml, Yb);
    attn_merge<<<512, 256, 0, stream>>>(Op, Ml, Yb);
    // out-proj (f32 out + bias)
    gemm2<1><<<256, 256, 0, stream>>>(Yb, Wob, bo, nullptr, nullptr,
                                      nullptr, nullptr, out);
}